// Round 2
// baseline (414.203 us; speedup 1.0000x reference)
//
#include <hip/hip_runtime.h>
#include <stdint.h>

typedef _Float16 f16;
typedef __attribute__((ext_vector_type(8))) _Float16 f16x8;
typedef __attribute__((ext_vector_type(4))) float f32x4;

// ---------------- threefry2x32 (JAX, key = (0,42)) ----------------
__device__ __forceinline__ uint32_t rotl32(uint32_t x, uint32_t n){ return (x<<n)|(x>>(32u-n)); }

__device__ __forceinline__ void threefry2x32(uint32_t c0, uint32_t c1, uint32_t& o0, uint32_t& o1){
  const uint32_t ks0 = 0u, ks1 = 42u, ks2 = 0x1BD11BDAu ^ 0u ^ 42u;
  uint32_t x0 = c0 + ks0, x1 = c1 + ks1;
#define TF_RND(R) { x0 += x1; x1 = rotl32(x1, R); x1 ^= x0; }
  TF_RND(13u) TF_RND(15u) TF_RND(26u) TF_RND(6u)
  x0 += ks1; x1 += ks2 + 1u;
  TF_RND(17u) TF_RND(29u) TF_RND(16u) TF_RND(24u)
  x0 += ks2; x1 += ks0 + 2u;
  TF_RND(13u) TF_RND(15u) TF_RND(26u) TF_RND(6u)
  x0 += ks0; x1 += ks1 + 3u;
  TF_RND(17u) TF_RND(29u) TF_RND(16u) TF_RND(24u)
  x0 += ks1; x1 += ks2 + 4u;
  TF_RND(13u) TF_RND(15u) TF_RND(26u) TF_RND(6u)
  x0 += ks2; x1 += ks0 + 5u;
#undef TF_RND
  o0 = x0; o1 = x1;
}

__device__ __forceinline__ bool tf_keep(uint32_t bits){
  // JAX uniform: bitcast((bits>>9)|0x3f800000) - 1.0 ; keep = u < 0.9f
  float u = __uint_as_float((bits >> 9) | 0x3f800000u) - 1.0f;
  return u < 0.9f;
}

// JAX >= 0.4.36 default: threefry_partitionable. For flat index i (size < 2^32):
//   (w0,w1) = threefry2x32(key, (hi32(i)=0, lo32(i)=i));  bits[i] = w0 ^ w1
__global__ __launch_bounds__(256) void mask_kernel(unsigned long long* __restrict__ mask){
  const uint32_t N = 67108864u;   // 2*8*2048*2048
  uint32_t stride = gridDim.x * blockDim.x;
  for (uint32_t i = blockIdx.x*blockDim.x + threadIdx.x; i < N; i += stride){
    uint32_t o0, o1;
    threefry2x32(0u, i, o0, o1);
    unsigned long long b = __ballot(tf_keep(o0 ^ o1));
    if ((threadIdx.x & 63) == 0) mask[i >> 6] = b;   // lane0's i is 64-aligned wave base
  }
}

// ---------------- Wo transpose to f16 [1024][64] ----------------
__global__ void wot_kernel(const float* __restrict__ Wo, f16* __restrict__ WoT){
  int t = blockIdx.x*blockDim.x + threadIdx.x;   // 65536
  int n = t & 1023, k = t >> 10;
  WoT[(long)n*64 + k] = (f16)Wo[(long)k*1024 + n];
}

// ---------------- projections: qp = 2*(query@Wq+bq) f16 [M][64];
//                  kp = key@Wk+bk f16 [M][64]; vpT = (value@Wv+bv)^T f16 [bh][64][2048]
__global__ __launch_bounds__(256) void proj_kernel(
    const float* __restrict__ query, const float* __restrict__ keyp, const float* __restrict__ value,
    const float* __restrict__ Wq, const float* __restrict__ bq,
    const float* __restrict__ Wk, const float* __restrict__ bk,
    const float* __restrict__ Wv, const float* __restrict__ bv,
    f16* __restrict__ qp, f16* __restrict__ kp, f16* __restrict__ vpT)
{
  __shared__ __align__(16) f16 Alds[64][40];   // rows x k (80B stride = 5*16B)
  __shared__ __align__(16) f16 Wlds[64][40];   // [col][k] transposed
  const int tid = threadIdx.x;
  const int lane = tid & 63, wave = tid >> 6;
  const int llo = lane & 15, lhi = lane >> 4;
  const int which = blockIdx.y;
  const float* A    = which==0 ? query : (which==1 ? keyp : value);
  const float* W    = which==0 ? Wq    : (which==1 ? Wk   : Wv);
  const float* bias = which==0 ? bq    : (which==1 ? bk   : bv);
  const long m0 = (long)blockIdx.x * 64;

  f32x4 acc[4];
  #pragma unroll
  for (int n=0;n<4;n++){
    float bb = bias[16*n + llo];
    acc[n][0]=bb; acc[n][1]=bb; acc[n][2]=bb; acc[n][3]=bb;
  }

  const int ar = tid >> 2;            // 0..63
  const int ac = (tid & 3) * 8;
  const int wcol = tid & 63;
  const int wk = (tid >> 6) * 8;

  for (int k0 = 0; k0 < 1024; k0 += 32){
    {
      const float* asrc = A + (m0 + ar)*1024 + k0 + ac;
      float4 v0 = *(const float4*)asrc;
      float4 v1 = *(const float4*)(asrc + 4);
      f16* ad = &Alds[ar][ac];
      ad[0]=(f16)v0.x; ad[1]=(f16)v0.y; ad[2]=(f16)v0.z; ad[3]=(f16)v0.w;
      ad[4]=(f16)v1.x; ad[5]=(f16)v1.y; ad[6]=(f16)v1.z; ad[7]=(f16)v1.w;
      f16 wt[8];
      #pragma unroll
      for (int j=0;j<8;j++) wt[j] = (f16)W[(long)(k0+wk+j)*64 + wcol];
      *(f16x8*)&Wlds[wcol][wk] = *(f16x8*)wt;
    }
    __syncthreads();
    f16x8 af = *(const f16x8*)&Alds[wave*16 + llo][lhi*8];
    #pragma unroll
    for (int n=0;n<4;n++){
      f16x8 bf = *(const f16x8*)&Wlds[16*n + llo][lhi*8];
      acc[n] = __builtin_amdgcn_mfma_f32_16x16x32_f16(af, bf, acc[n], 0,0,0);
    }
    __syncthreads();
  }

  if (which < 2){
    const float scale = (which==0) ? 2.0f : 1.0f;   // fold dk=2.0 into q
    f16* dst = (which==0) ? qp : kp;
    #pragma unroll
    for (int n=0;n<4;n++)
      #pragma unroll
      for (int j=0;j<4;j++){
        long row = m0 + wave*16 + lhi*4 + j;
        dst[row*64 + 16*n + llo] = (f16)(acc[n][j]*scale);
      }
  } else {
    long row0 = m0 + wave*16 + lhi*4;
    long bh = row0 >> 11;
    long lr = row0 & 2047;
    #pragma unroll
    for (int n=0;n<4;n++){
      union { f16 h[4]; ushort4 u; } pk;
      #pragma unroll
      for (int j=0;j<4;j++) pk.h[j] = (f16)acc[n][j];
      *(ushort4*)&vpT[(bh*64 + 16*n + llo)*2048 + lr] = pk.u;
    }
  }
}

// ---------------- flash attention with exact-JAX dropout ----------------
__global__ __launch_bounds__(256) void flash_kernel(
    const f16* __restrict__ qp, const f16* __restrict__ kp, const f16* __restrict__ vpT,
    const unsigned long long* __restrict__ mask, float* __restrict__ out64)
{
  __shared__ __align__(16) f16 Klds[64][72];     // kv x dim (144B stride)
  __shared__ __align__(16) f16 Vlds[64][72];     // vdim x kv
  __shared__ __align__(16) f16 Plds[4][16][72];  // per-wave P relayout
  const int tid = threadIdx.x;
  const int lane = tid & 63, wave = tid >> 6;
  const int llo = lane & 15, lhi = lane >> 4;
  const int bh = blockIdx.y;
  const int q0 = blockIdx.x * 64;

  const f16* qbase = qp + ((long)bh*2048 + q0 + wave*16 + llo)*64 + lhi*8;
  f16x8 qf0 = *(const f16x8*)qbase;
  f16x8 qf1 = *(const f16x8*)(qbase + 32);

  f32x4 O[4];
  float mrun[4], lrun[4];
  #pragma unroll
  for (int n=0;n<4;n++){ O[n][0]=0.f;O[n][1]=0.f;O[n][2]=0.f;O[n][3]=0.f; }
  #pragma unroll
  for (int j=0;j<4;j++){ mrun[j] = -__builtin_inff(); lrun[j]=0.f; }

  const int sr = tid >> 2;            // stage row 0..63
  const int sc = (tid & 3) * 16;      // stage col (f16)
  const f16* kbh = kp + (long)bh*2048*64;
  const f16* vbh = vpT + (long)bh*64*2048;

  for (int kv0 = 0; kv0 < 2048; kv0 += 64){
    {
      const f16* src = kbh + (long)(kv0 + sr)*64 + sc;
      f16x8 t0 = *(const f16x8*)src;
      f16x8 t1 = *(const f16x8*)(src+8);
      *(f16x8*)&Klds[sr][sc]   = t0;
      *(f16x8*)&Klds[sr][sc+8] = t1;
      const f16* vsrc = vbh + (long)sr*2048 + kv0 + sc;
      f16x8 u0 = *(const f16x8*)vsrc;
      f16x8 u1 = *(const f16x8*)(vsrc+8);
      *(f16x8*)&Vlds[sr][sc]   = u0;
      *(f16x8*)&Vlds[sr][sc+8] = u1;
    }
    __syncthreads();

    f32x4 s[4];
    #pragma unroll
    for (int n=0;n<4;n++){ s[n][0]=0.f;s[n][1]=0.f;s[n][2]=0.f;s[n][3]=0.f; }
    #pragma unroll
    for (int n=0;n<4;n++){
      f16x8 kf0 = *(const f16x8*)&Klds[16*n+llo][lhi*8];
      s[n] = __builtin_amdgcn_mfma_f32_16x16x32_f16(qf0, kf0, s[n], 0,0,0);
      f16x8 kf1 = *(const f16x8*)&Klds[16*n+llo][32+lhi*8];
      s[n] = __builtin_amdgcn_mfma_f32_16x16x32_f16(qf1, kf1, s[n], 0,0,0);
    }
    // online softmax: row r = lhi*4+j lives across the 16 lanes sharing lhi
    float pmax[4];
    #pragma unroll
    for (int j=0;j<4;j++)
      pmax[j] = fmaxf(fmaxf(s[0][j],s[1][j]), fmaxf(s[2][j],s[3][j]));
    #pragma unroll
    for (int off=1; off<16; off<<=1){
      #pragma unroll
      for (int j=0;j<4;j++) pmax[j] = fmaxf(pmax[j], __shfl_xor(pmax[j], off));
    }
    float esc[4];
    #pragma unroll
    for (int j=0;j<4;j++){
      float mnew = fmaxf(mrun[j], pmax[j]);
      esc[j] = __expf(mrun[j] - mnew);
      mrun[j] = mnew;
    }
    float p[4][4]; float lsum[4] = {0.f,0.f,0.f,0.f};
    #pragma unroll
    for (int n=0;n<4;n++)
      #pragma unroll
      for (int j=0;j<4;j++){
        p[n][j] = __expf(s[n][j] - mrun[j]);
        lsum[j] += p[n][j];
      }
    #pragma unroll
    for (int off=1; off<16; off<<=1){
      #pragma unroll
      for (int j=0;j<4;j++) lsum[j] += __shfl_xor(lsum[j], off);
    }
    #pragma unroll
    for (int j=0;j<4;j++) lrun[j] = lrun[j]*esc[j] + lsum[j];
    #pragma unroll
    for (int n=0;n<4;n++)
      #pragma unroll
      for (int j=0;j<4;j++) O[n][j] *= esc[j];

    // dropout (denominator stays unmasked) + P -> LDS (f16, A-frag layout)
    const long jbase = (((long)bh*2048 + q0 + wave*16 + lhi*4)*2048) + kv0;
    #pragma unroll
    for (int j=0;j<4;j++){
      unsigned long long mw = mask[(jbase + (long)j*2048) >> 6];
      #pragma unroll
      for (int n=0;n<4;n++){
        float pm = ((mw >> (16*n + llo)) & 1ull) ? p[n][j]*(1.0f/0.9f) : 0.0f;
        Plds[wave][lhi*4+j][16*n+llo] = (f16)pm;
      }
    }
    f16x8 pa0 = *(const f16x8*)&Plds[wave][llo][lhi*8];
    f16x8 pa1 = *(const f16x8*)&Plds[wave][llo][32+lhi*8];
    #pragma unroll
    for (int n=0;n<4;n++){
      f16x8 vf0 = *(const f16x8*)&Vlds[16*n+llo][lhi*8];
      O[n] = __builtin_amdgcn_mfma_f32_16x16x32_f16(pa0, vf0, O[n], 0,0,0);
      f16x8 vf1 = *(const f16x8*)&Vlds[16*n+llo][32+lhi*8];
      O[n] = __builtin_amdgcn_mfma_f32_16x16x32_f16(pa1, vf1, O[n], 0,0,0);
    }
    __syncthreads();
  }
  float rl[4];
  #pragma unroll
  for (int j=0;j<4;j++) rl[j] = 1.0f / lrun[j];
  long rbase = (long)bh*2048 + q0 + wave*16 + lhi*4;
  #pragma unroll
  for (int n=0;n<4;n++)
    #pragma unroll
    for (int j=0;j<4;j++)
      out64[(rbase + j)*64 + 16*n + llo] = O[n][j]*rl[j];
}

// ---------------- out = out64 @ Wo + bo ----------------
__global__ __launch_bounds__(256) void final_kernel(
    const float* __restrict__ out64, const f16* __restrict__ WoT,
    const float* __restrict__ bo, float* __restrict__ out)
{
  const int tid = threadIdx.x;
  const int lane = tid & 63, wave = tid >> 6;
  const int llo = lane & 15, lhi = lane >> 4;
  const long m0 = (long)blockIdx.x * 64;
  const int nb = blockIdx.y * 256;
  const float* abase = out64 + (m0 + wave*16 + llo)*64 + lhi*8;
  float4 a0 = *(const float4*)abase;
  float4 a1 = *(const float4*)(abase+4);
  float4 a2 = *(const float4*)(abase+32);
  float4 a3 = *(const float4*)(abase+36);
  f16x8 af0, af1;
  af0[0]=(f16)a0.x; af0[1]=(f16)a0.y; af0[2]=(f16)a0.z; af0[3]=(f16)a0.w;
  af0[4]=(f16)a1.x; af0[5]=(f16)a1.y; af0[6]=(f16)a1.z; af0[7]=(f16)a1.w;
  af1[0]=(f16)a2.x; af1[1]=(f16)a2.y; af1[2]=(f16)a2.z; af1[3]=(f16)a2.w;
  af1[4]=(f16)a3.x; af1[5]=(f16)a3.y; af1[6]=(f16)a3.z; af1[7]=(f16)a3.w;
  for (int n0 = nb; n0 < nb+256; n0 += 16){
    f16x8 b0 = *(const f16x8*)&WoT[(long)(n0+llo)*64 + lhi*8];
    f16x8 b1 = *(const f16x8*)&WoT[(long)(n0+llo)*64 + 32 + lhi*8];
    float bb = bo[n0+llo];
    f32x4 c; c[0]=bb; c[1]=bb; c[2]=bb; c[3]=bb;
    c = __builtin_amdgcn_mfma_f32_16x16x32_f16(af0, b0, c, 0,0,0);
    c = __builtin_amdgcn_mfma_f32_16x16x32_f16(af1, b1, c, 0,0,0);
    long ro = m0 + wave*16 + lhi*4;
    #pragma unroll
    for (int j=0;j<4;j++)
      out[(ro + j)*1024 + n0 + llo] = c[j];
  }
}

extern "C" void kernel_launch(void* const* d_in, const int* in_sizes, int n_in,
                              void* d_out, int out_size, void* d_ws, size_t ws_size,
                              hipStream_t stream){
  const float* query = (const float*)d_in[0];
  const float* key   = (const float*)d_in[1];
  const float* value = (const float*)d_in[2];
  const float* Wq = (const float*)d_in[3];
  const float* bq = (const float*)d_in[4];
  const float* Wk = (const float*)d_in[5];
  const float* bk = (const float*)d_in[6];
  const float* Wv = (const float*)d_in[7];
  const float* bv = (const float*)d_in[8];
  const float* Wo = (const float*)d_in[9];
  const float* bo = (const float*)d_in[10];
  float* out = (float*)d_out;

  char* ws = (char*)d_ws;
  f16* qp   = (f16*)(ws);                               // 4 MiB
  f16* kp   = (f16*)(ws + ((size_t)4<<20));             // 4 MiB
  f16* vpT  = (f16*)(ws + ((size_t)8<<20));             // 4 MiB
  float* out64 = (float*)(ws + ((size_t)12<<20));       // 8 MiB
  f16* WoT  = (f16*)(ws + ((size_t)20<<20));            // 128 KiB
  unsigned long long* mask = (unsigned long long*)(ws + ((size_t)21<<20)); // 8 MiB

  mask_kernel<<<dim3(4096), dim3(256), 0, stream>>>(mask);
  wot_kernel<<<dim3(256), dim3(256), 0, stream>>>(Wo, WoT);
  proj_kernel<<<dim3(512,3), dim3(256), 0, stream>>>(query,key,value,Wq,bq,Wk,bk,Wv,bv,qp,kp,vpT);
  flash_kernel<<<dim3(32,16), dim3(256), 0, stream>>>(qp,kp,vpT,mask,out64);
  final_kernel<<<dim3(512,4), dim3(256), 0, stream>>>(out64,WoT,bo,out);
}

// Round 3
// 327.415 us; speedup vs baseline: 1.2651x; 1.2651x over previous
//
#include <hip/hip_runtime.h>
#include <stdint.h>

typedef _Float16 f16;
typedef __attribute__((ext_vector_type(8))) _Float16 f16x8;
typedef __attribute__((ext_vector_type(4))) float f32x4;

// ---------------- threefry2x32 (JAX partitionable, key=(0,42), counts=(0,i)) ----
// returns w0 ^ w1 (JAX xor-fold for 32-bit draws)
__device__ __forceinline__ uint32_t tf_bits(uint32_t i){
  const uint32_t ks1 = 42u, ks2 = 0x1BD11BDAu ^ 42u;
  uint32_t x0 = 0u, x1 = i + 42u;
#define R4(a,b,c,d) \
  x0 += x1; x1 = __builtin_rotateleft32(x1,a); x1 ^= x0; \
  x0 += x1; x1 = __builtin_rotateleft32(x1,b); x1 ^= x0; \
  x0 += x1; x1 = __builtin_rotateleft32(x1,c); x1 ^= x0; \
  x0 += x1; x1 = __builtin_rotateleft32(x1,d); x1 ^= x0;
  R4(13,15,26,6)  x0 += ks1; x1 += ks2 + 1u;
  R4(17,29,16,24) x0 += ks2; x1 += 2u;         // ks0 = 0
  R4(13,15,26,6)               x1 += ks1 + 3u; // x0 += ks0 = +0
  R4(17,29,16,24) x0 += ks1; x1 += ks2 + 4u;
  R4(13,15,26,6)  x0 += ks2; x1 += 5u;         // ks0 = 0
#undef R4
  return x0 ^ x1;
}
// keep = uniform(bits) < 0.9f  ⟺  (bits>>9) < 0x733333  ⟺  bits < 0xE6666600
__device__ __forceinline__ bool tf_keep(uint32_t bits){ return bits < 0xE6666600u; }

// ---------------- fused front: mask (VALU) + proj (HBM) + wot, role by blockIdx --
// grid = 5888 blocks; per group of 23: 16 mask, 6 proj, 1 wot
__global__ __launch_bounds__(256) void front_kernel(
    const float* __restrict__ query, const float* __restrict__ keyp, const float* __restrict__ value,
    const float* __restrict__ Wq, const float* __restrict__ bq,
    const float* __restrict__ Wk, const float* __restrict__ bk,
    const float* __restrict__ Wv, const float* __restrict__ bv,
    const float* __restrict__ Wo,
    f16* __restrict__ qp, f16* __restrict__ kp, f16* __restrict__ vpT,
    f16* __restrict__ WoT, unsigned long long* __restrict__ mask)
{
  __shared__ __align__(16) f16 Alds[64][40];   // rows x k (80B stride)
  __shared__ __align__(16) f16 Wlds[64][40];   // [col][k]
  const int bid = blockIdx.x;
  const int g = bid / 23, s = bid - g*23;
  const int tid = threadIdx.x;
  const int lane = tid & 63, wave = tid >> 6;
  const int llo = lane & 15, lhi = lane >> 4;

  if (s < 16){
    // ---- mask role: 4096 virtual blocks -> 16384 waves, 64 mask words each ----
    const uint32_t wv = (uint32_t)(g*16 + s)*4u + (uint32_t)wave;  // 0..16383
    unsigned long long* mp = mask + (size_t)wv*64u;
    const uint32_t ibase = wv*4096u + (uint32_t)lane;
    #pragma unroll 4
    for (int it = 0; it < 32; ++it){
      uint32_t i0 = ibase + (uint32_t)(it*128);
      uint32_t b0v = tf_bits(i0);
      uint32_t b1v = tf_bits(i0 + 64u);
      unsigned long long b0 = __ballot(tf_keep(b0v));
      unsigned long long b1 = __ballot(tf_keep(b1v));
      if (lane == 0){
        ulonglong2 w; w.x = b0; w.y = b1;
        *(ulonglong2*)&mp[it*2] = w;
      }
    }
    return;
  }

  if (s == 22){
    // ---- wot role: 256 virtual blocks, one element per thread ----
    int t = g*256 + tid;
    int n = t & 1023, k = t >> 10;
    WoT[(long)n*64 + k] = (f16)Wo[(long)k*1024 + n];
    return;
  }

  // ---- proj role: p in [0,1536) ----
  const int p = g*6 + (s - 16);
  const int which = p >> 9;           // 0..2
  const long m0 = (long)(p & 511) * 64;
  const float* A    = which==0 ? query : (which==1 ? keyp : value);
  const float* W    = which==0 ? Wq    : (which==1 ? Wk   : Wv);
  const float* bias = which==0 ? bq    : (which==1 ? bk   : bv);

  f32x4 acc[4];
  #pragma unroll
  for (int n=0;n<4;n++){
    float bb = bias[16*n + llo];
    acc[n][0]=bb; acc[n][1]=bb; acc[n][2]=bb; acc[n][3]=bb;
  }

  const int ar = tid >> 2;            // 0..63
  const int ac = (tid & 3) * 8;
  const int wcol = tid & 63;
  const int wk = (tid >> 6) * 8;

  for (int k0 = 0; k0 < 1024; k0 += 32){
    {
      const float* asrc = A + (m0 + ar)*1024 + k0 + ac;
      float4 v0 = *(const float4*)asrc;
      float4 v1 = *(const float4*)(asrc + 4);
      f16* ad = &Alds[ar][ac];
      ad[0]=(f16)v0.x; ad[1]=(f16)v0.y; ad[2]=(f16)v0.z; ad[3]=(f16)v0.w;
      ad[4]=(f16)v1.x; ad[5]=(f16)v1.y; ad[6]=(f16)v1.z; ad[7]=(f16)v1.w;
      f16 wt[8];
      #pragma unroll
      for (int j=0;j<8;j++) wt[j] = (f16)W[(long)(k0+wk+j)*64 + wcol];
      *(f16x8*)&Wlds[wcol][wk] = *(f16x8*)wt;
    }
    __syncthreads();
    f16x8 af = *(const f16x8*)&Alds[wave*16 + llo][lhi*8];
    #pragma unroll
    for (int n=0;n<4;n++){
      f16x8 bf = *(const f16x8*)&Wlds[16*n + llo][lhi*8];
      acc[n] = __builtin_amdgcn_mfma_f32_16x16x32_f16(af, bf, acc[n], 0,0,0);
    }
    __syncthreads();
  }

  if (which < 2){
    const float scale = (which==0) ? 2.0f : 1.0f;   // fold dk=2.0 into q
    f16* dst = (which==0) ? qp : kp;
    #pragma unroll
    for (int n=0;n<4;n++)
      #pragma unroll
      for (int j=0;j<4;j++){
        long row = m0 + wave*16 + lhi*4 + j;
        dst[row*64 + 16*n + llo] = (f16)(acc[n][j]*scale);
      }
  } else {
    long row0 = m0 + wave*16 + lhi*4;
    long bh = row0 >> 11;
    long lr = row0 & 2047;
    #pragma unroll
    for (int n=0;n<4;n++){
      union { f16 h[4]; ushort4 u; } pk;
      #pragma unroll
      for (int j=0;j<4;j++) pk.h[j] = (f16)acc[n][j];
      *(ushort4*)&vpT[(bh*64 + 16*n + llo)*2048 + lr] = pk.u;
    }
  }
}

// ---------------- flash attention with exact-JAX dropout ----------------
__global__ __launch_bounds__(256) void flash_kernel(
    const f16* __restrict__ qp, const f16* __restrict__ kp, const f16* __restrict__ vpT,
    const unsigned long long* __restrict__ mask, float* __restrict__ out64)
{
  __shared__ __align__(16) f16 Klds[64][72];     // kv x dim (144B stride)
  __shared__ __align__(16) f16 Vlds[64][72];     // vdim x kv
  __shared__ __align__(16) f16 Plds[4][16][72];  // per-wave P relayout
  const int tid = threadIdx.x;
  const int lane = tid & 63, wave = tid >> 6;
  const int llo = lane & 15, lhi = lane >> 4;
  const int bh = blockIdx.y;
  const int q0 = blockIdx.x * 64;

  const f16* qbase = qp + ((long)bh*2048 + q0 + wave*16 + llo)*64 + lhi*8;
  f16x8 qf0 = *(const f16x8*)qbase;
  f16x8 qf1 = *(const f16x8*)(qbase + 32);

  f32x4 O[4];
  float mrun[4], lrun[4];
  #pragma unroll
  for (int n=0;n<4;n++){ O[n][0]=0.f;O[n][1]=0.f;O[n][2]=0.f;O[n][3]=0.f; }
  #pragma unroll
  for (int j=0;j<4;j++){ mrun[j] = -__builtin_inff(); lrun[j]=0.f; }

  const int sr = tid >> 2;            // stage row 0..63
  const int sc = (tid & 3) * 16;      // stage col (f16)
  const f16* kbh = kp + (long)bh*2048*64;
  const f16* vbh = vpT + (long)bh*64*2048;

  for (int kv0 = 0; kv0 < 2048; kv0 += 64){
    {
      const f16* src = kbh + (long)(kv0 + sr)*64 + sc;
      f16x8 t0 = *(const f16x8*)src;
      f16x8 t1 = *(const f16x8*)(src+8);
      *(f16x8*)&Klds[sr][sc]   = t0;
      *(f16x8*)&Klds[sr][sc+8] = t1;
      const f16* vsrc = vbh + (long)sr*2048 + kv0 + sc;
      f16x8 u0 = *(const f16x8*)vsrc;
      f16x8 u1 = *(const f16x8*)(vsrc+8);
      *(f16x8*)&Vlds[sr][sc]   = u0;
      *(f16x8*)&Vlds[sr][sc+8] = u1;
    }
    __syncthreads();

    f32x4 s[4];
    #pragma unroll
    for (int n=0;n<4;n++){ s[n][0]=0.f;s[n][1]=0.f;s[n][2]=0.f;s[n][3]=0.f; }
    #pragma unroll
    for (int n=0;n<4;n++){
      f16x8 kf0 = *(const f16x8*)&Klds[16*n+llo][lhi*8];
      s[n] = __builtin_amdgcn_mfma_f32_16x16x32_f16(qf0, kf0, s[n], 0,0,0);
      f16x8 kf1 = *(const f16x8*)&Klds[16*n+llo][32+lhi*8];
      s[n] = __builtin_amdgcn_mfma_f32_16x16x32_f16(qf1, kf1, s[n], 0,0,0);
    }
    // online softmax: row r = lhi*4+j lives across the 16 lanes sharing lhi
    float pmax[4];
    #pragma unroll
    for (int j=0;j<4;j++)
      pmax[j] = fmaxf(fmaxf(s[0][j],s[1][j]), fmaxf(s[2][j],s[3][j]));
    #pragma unroll
    for (int off=1; off<16; off<<=1){
      #pragma unroll
      for (int j=0;j<4;j++) pmax[j] = fmaxf(pmax[j], __shfl_xor(pmax[j], off));
    }
    float esc[4];
    #pragma unroll
    for (int j=0;j<4;j++){
      float mnew = fmaxf(mrun[j], pmax[j]);
      esc[j] = __expf(mrun[j] - mnew);
      mrun[j] = mnew;
    }
    float p[4][4]; float lsum[4] = {0.f,0.f,0.f,0.f};
    #pragma unroll
    for (int n=0;n<4;n++)
      #pragma unroll
      for (int j=0;j<4;j++){
        p[n][j] = __expf(s[n][j] - mrun[j]);
        lsum[j] += p[n][j];
      }
    #pragma unroll
    for (int off=1; off<16; off<<=1){
      #pragma unroll
      for (int j=0;j<4;j++) lsum[j] += __shfl_xor(lsum[j], off);
    }
    #pragma unroll
    for (int j=0;j<4;j++) lrun[j] = lrun[j]*esc[j] + lsum[j];
    #pragma unroll
    for (int n=0;n<4;n++)
      #pragma unroll
      for (int j=0;j<4;j++) O[n][j] *= esc[j];

    // dropout (denominator stays unmasked) + P -> LDS (f16, A-frag layout)
    const long jbase = (((long)bh*2048 + q0 + wave*16 + lhi*4)*2048) + kv0;
    #pragma unroll
    for (int j=0;j<4;j++){
      unsigned long long mw = mask[(jbase + (long)j*2048) >> 6];
      #pragma unroll
      for (int n=0;n<4;n++){
        float pm = ((mw >> (16*n + llo)) & 1ull) ? p[n][j]*(1.0f/0.9f) : 0.0f;
        Plds[wave][lhi*4+j][16*n+llo] = (f16)pm;
      }
    }
    f16x8 pa0 = *(const f16x8*)&Plds[wave][llo][lhi*8];
    f16x8 pa1 = *(const f16x8*)&Plds[wave][llo][32+lhi*8];
    #pragma unroll
    for (int n=0;n<4;n++){
      f16x8 vf0 = *(const f16x8*)&Vlds[16*n+llo][lhi*8];
      O[n] = __builtin_amdgcn_mfma_f32_16x16x32_f16(pa0, vf0, O[n], 0,0,0);
      f16x8 vf1 = *(const f16x8*)&Vlds[16*n+llo][32+lhi*8];
      O[n] = __builtin_amdgcn_mfma_f32_16x16x32_f16(pa1, vf1, O[n], 0,0,0);
    }
    __syncthreads();
  }
  float rl[4];
  #pragma unroll
  for (int j=0;j<4;j++) rl[j] = 1.0f / lrun[j];
  long rbase = (long)bh*2048 + q0 + wave*16 + lhi*4;
  #pragma unroll
  for (int n=0;n<4;n++)
    #pragma unroll
    for (int j=0;j<4;j++)
      out64[(rbase + j)*64 + 16*n + llo] = O[n][j]*rl[j];
}

// ---------------- out = out64 @ Wo + bo ----------------
__global__ __launch_bounds__(256) void final_kernel(
    const float* __restrict__ out64, const f16* __restrict__ WoT,
    const float* __restrict__ bo, float* __restrict__ out)
{
  const int tid = threadIdx.x;
  const int lane = tid & 63, wave = tid >> 6;
  const int llo = lane & 15, lhi = lane >> 4;
  const long m0 = (long)blockIdx.x * 64;
  const int nb = blockIdx.y * 256;
  const float* abase = out64 + (m0 + wave*16 + llo)*64 + lhi*8;
  float4 a0 = *(const float4*)abase;
  float4 a1 = *(const float4*)(abase+4);
  float4 a2 = *(const float4*)(abase+32);
  float4 a3 = *(const float4*)(abase+36);
  f16x8 af0, af1;
  af0[0]=(f16)a0.x; af0[1]=(f16)a0.y; af0[2]=(f16)a0.z; af0[3]=(f16)a0.w;
  af0[4]=(f16)a1.x; af0[5]=(f16)a1.y; af0[6]=(f16)a1.z; af0[7]=(f16)a1.w;
  af1[0]=(f16)a2.x; af1[1]=(f16)a2.y; af1[2]=(f16)a2.z; af1[3]=(f16)a2.w;
  af1[4]=(f16)a3.x; af1[5]=(f16)a3.y; af1[6]=(f16)a3.z; af1[7]=(f16)a3.w;
  for (int n0 = nb; n0 < nb+256; n0 += 16){
    f16x8 b0 = *(const f16x8*)&WoT[(long)(n0+llo)*64 + lhi*8];
    f16x8 b1 = *(const f16x8*)&WoT[(long)(n0+llo)*64 + 32 + lhi*8];
    float bb = bo[n0+llo];
    f32x4 c; c[0]=bb; c[1]=bb; c[2]=bb; c[3]=bb;
    c = __builtin_amdgcn_mfma_f32_16x16x32_f16(af0, b0, c, 0,0,0);
    c = __builtin_amdgcn_mfma_f32_16x16x32_f16(af1, b1, c, 0,0,0);
    long ro = m0 + wave*16 + lhi*4;
    #pragma unroll
    for (int j=0;j<4;j++)
      out[(ro + j)*1024 + n0 + llo] = c[j];
  }
}

extern "C" void kernel_launch(void* const* d_in, const int* in_sizes, int n_in,
                              void* d_out, int out_size, void* d_ws, size_t ws_size,
                              hipStream_t stream){
  const float* query = (const float*)d_in[0];
  const float* key   = (const float*)d_in[1];
  const float* value = (const float*)d_in[2];
  const float* Wq = (const float*)d_in[3];
  const float* bq = (const float*)d_in[4];
  const float* Wk = (const float*)d_in[5];
  const float* bk = (const float*)d_in[6];
  const float* Wv = (const float*)d_in[7];
  const float* bv = (const float*)d_in[8];
  const float* Wo = (const float*)d_in[9];
  const float* bo = (const float*)d_in[10];
  float* out = (float*)d_out;

  char* ws = (char*)d_ws;
  f16* qp   = (f16*)(ws);                               // 4 MiB
  f16* kp   = (f16*)(ws + ((size_t)4<<20));             // 4 MiB
  f16* vpT  = (f16*)(ws + ((size_t)8<<20));             // 4 MiB
  float* out64 = (float*)(ws + ((size_t)12<<20));       // 8 MiB
  f16* WoT  = (f16*)(ws + ((size_t)20<<20));            // 128 KiB
  unsigned long long* mask = (unsigned long long*)(ws + ((size_t)21<<20)); // 8 MiB

  front_kernel<<<dim3(5888), dim3(256), 0, stream>>>(
      query,key,value,Wq,bq,Wk,bk,Wv,bv,Wo,qp,kp,vpT,WoT,mask);
  flash_kernel<<<dim3(32,16), dim3(256), 0, stream>>>(qp,kp,vpT,mask,out64);
  final_kernel<<<dim3(512,4), dim3(256), 0, stream>>>(out64,WoT,bo,out);
}

// Round 4
// 302.846 us; speedup vs baseline: 1.3677x; 1.0811x over previous
//
#include <hip/hip_runtime.h>
#include <stdint.h>

typedef _Float16 f16;
typedef __attribute__((ext_vector_type(8))) _Float16 f16x8;
typedef __attribute__((ext_vector_type(4))) float f32x4;

// ---------------- threefry2x32 (JAX partitionable, key=(0,42), counts=(0,i)) ----
// returns w0 ^ w1 (JAX xor-fold for 32-bit draws). rotl forced to v_alignbit_b32.
__device__ __forceinline__ uint32_t rotl1(uint32_t x, uint32_t n){
  return __builtin_amdgcn_alignbit(x, x, 32u - n);
}
__device__ __forceinline__ uint32_t tf_bits(uint32_t i){
  const uint32_t ks1 = 42u, ks2 = 0x1BD11BDAu ^ 42u;
  uint32_t x0 = 0u, x1 = i + 42u;
#define R4(a,b,c,d) \
  x0 += x1; x1 = rotl1(x1,a); x1 ^= x0; \
  x0 += x1; x1 = rotl1(x1,b); x1 ^= x0; \
  x0 += x1; x1 = rotl1(x1,c); x1 ^= x0; \
  x0 += x1; x1 = rotl1(x1,d); x1 ^= x0;
  R4(13,15,26,6)  x0 += ks1; x1 += ks2 + 1u;
  R4(17,29,16,24) x0 += ks2; x1 += 2u;         // ks0 = 0
  R4(13,15,26,6)               x1 += ks1 + 3u; // x0 += ks0 = +0
  R4(17,29,16,24) x0 += ks1; x1 += ks2 + 4u;
  R4(13,15,26,6)  x0 += ks2; x1 += 5u;         // ks0 = 0
#undef R4
  return x0 ^ x1;
}
// keep = uniform(bits) < 0.9f  ⟺  (bits>>9) < 0x733333  ⟺  bits < 0xE6666600
__device__ __forceinline__ bool tf_keep(uint32_t bits){ return bits < 0xE6666600u; }

// ---------------- K1: projections + Wo transpose (HBM-bound) ----------------
// blocks 0..1535: proj; 1536..1791: wot
__global__ __launch_bounds__(256) void proj_kernel(
    const float* __restrict__ query, const float* __restrict__ keyp, const float* __restrict__ value,
    const float* __restrict__ Wq, const float* __restrict__ bq,
    const float* __restrict__ Wk, const float* __restrict__ bk,
    const float* __restrict__ Wv, const float* __restrict__ bv,
    const float* __restrict__ Wo,
    f16* __restrict__ qp, f16* __restrict__ kp, f16* __restrict__ vpT,
    f16* __restrict__ WoT)
{
  __shared__ __align__(16) f16 Alds[64][40];   // rows x k (80B stride)
  __shared__ __align__(16) f16 Wlds[64][40];   // [col][k]
  const int bid = blockIdx.x;
  const int tid = threadIdx.x;
  const int lane = tid & 63, wave = tid >> 6;
  const int llo = lane & 15, lhi = lane >> 4;

  if (bid >= 1536){
    // ---- wot role ----
    int t = (bid - 1536)*256 + tid;
    int n = t & 1023, k = t >> 10;
    WoT[(long)n*64 + k] = (f16)Wo[(long)k*1024 + n];
    return;
  }

  const int p = bid;
  const int which = p >> 9;           // 0..2
  const long m0 = (long)(p & 511) * 64;
  const float* A    = which==0 ? query : (which==1 ? keyp : value);
  const float* W    = which==0 ? Wq    : (which==1 ? Wk   : Wv);
  const float* bias = which==0 ? bq    : (which==1 ? bk   : bv);

  f32x4 acc[4];
  #pragma unroll
  for (int n=0;n<4;n++){
    float bb = bias[16*n + llo];
    acc[n][0]=bb; acc[n][1]=bb; acc[n][2]=bb; acc[n][3]=bb;
  }

  const int ar = tid >> 2;            // 0..63
  const int ac = (tid & 3) * 8;
  const int wcol = tid & 63;
  const int wk = (tid >> 6) * 8;

  for (int k0 = 0; k0 < 1024; k0 += 32){
    {
      const float* asrc = A + (m0 + ar)*1024 + k0 + ac;
      float4 v0 = *(const float4*)asrc;
      float4 v1 = *(const float4*)(asrc + 4);
      f16* ad = &Alds[ar][ac];
      ad[0]=(f16)v0.x; ad[1]=(f16)v0.y; ad[2]=(f16)v0.z; ad[3]=(f16)v0.w;
      ad[4]=(f16)v1.x; ad[5]=(f16)v1.y; ad[6]=(f16)v1.z; ad[7]=(f16)v1.w;
      f16 wt[8];
      #pragma unroll
      for (int j=0;j<8;j++) wt[j] = (f16)W[(long)(k0+wk+j)*64 + wcol];
      *(f16x8*)&Wlds[wcol][wk] = *(f16x8*)wt;
    }
    __syncthreads();
    f16x8 af = *(const f16x8*)&Alds[wave*16 + llo][lhi*8];
    #pragma unroll
    for (int n=0;n<4;n++){
      f16x8 bf = *(const f16x8*)&Wlds[16*n + llo][lhi*8];
      acc[n] = __builtin_amdgcn_mfma_f32_16x16x32_f16(af, bf, acc[n], 0,0,0);
    }
    __syncthreads();
  }

  if (which < 2){
    const float scale = (which==0) ? 2.0f : 1.0f;   // fold dk=2.0 into q
    f16* dst = (which==0) ? qp : kp;
    #pragma unroll
    for (int n=0;n<4;n++)
      #pragma unroll
      for (int j=0;j<4;j++){
        long row = m0 + wave*16 + lhi*4 + j;
        dst[row*64 + 16*n + llo] = (f16)(acc[n][j]*scale);
      }
  } else {
    long row0 = m0 + wave*16 + lhi*4;
    long bh = row0 >> 11;
    long lr = row0 & 2047;
    #pragma unroll
    for (int n=0;n<4;n++){
      union { f16 h[4]; ushort4 u; } pk;
      #pragma unroll
      for (int j=0;j<4;j++) pk.h[j] = (f16)acc[n][j];
      *(ushort4*)&vpT[(bh*64 + 16*n + llo)*2048 + lr] = pk.u;
    }
  }
}

// ---------------- K2: flash attention w/ inline threefry dropout + fused out-proj
__global__ __launch_bounds__(256) void flash_kernel(
    const f16* __restrict__ qp, const f16* __restrict__ kp, const f16* __restrict__ vpT,
    const f16* __restrict__ WoT, const float* __restrict__ bo, float* __restrict__ out)
{
  __shared__ __align__(16) f16 Klds[64][72];     // kv x dim (144B stride); reused for O in epilogue
  __shared__ __align__(16) f16 Vlds[64][72];     // vdim x kv
  __shared__ __align__(16) f16 Plds[4][16][72];  // per-wave P relayout
  const int tid = threadIdx.x;
  const int lane = tid & 63, wave = tid >> 6;
  const int llo = lane & 15, lhi = lane >> 4;
  const int bh = blockIdx.y;
  const int q0 = blockIdx.x * 64;

  const f16* qbase = qp + ((long)bh*2048 + q0 + wave*16 + llo)*64 + lhi*8;
  f16x8 qf0 = *(const f16x8*)qbase;
  f16x8 qf1 = *(const f16x8*)(qbase + 32);

  f32x4 O[4];
  float mrun[4], lrun[4];
  #pragma unroll
  for (int n=0;n<4;n++){ O[n][0]=0.f;O[n][1]=0.f;O[n][2]=0.f;O[n][3]=0.f; }
  #pragma unroll
  for (int j=0;j<4;j++){ mrun[j] = -__builtin_inff(); lrun[j]=0.f; }

  const int sr = tid >> 2;            // stage row 0..63
  const int sc = (tid & 3) * 16;      // stage col (f16)
  const f16* kbh = kp + (long)bh*2048*64;
  const f16* vbh = vpT + (long)bh*64*2048;

  for (int kv0 = 0; kv0 < 2048; kv0 += 64){
    {
      const f16* src = kbh + (long)(kv0 + sr)*64 + sc;
      f16x8 t0 = *(const f16x8*)src;
      f16x8 t1 = *(const f16x8*)(src+8);
      *(f16x8*)&Klds[sr][sc]   = t0;
      *(f16x8*)&Klds[sr][sc+8] = t1;
      const f16* vsrc = vbh + (long)sr*2048 + kv0 + sc;
      f16x8 u0 = *(const f16x8*)vsrc;
      f16x8 u1 = *(const f16x8*)(vsrc+8);
      *(f16x8*)&Vlds[sr][sc]   = u0;
      *(f16x8*)&Vlds[sr][sc+8] = u1;
    }
    __syncthreads();

    f32x4 s[4];
    #pragma unroll
    for (int n=0;n<4;n++){ s[n][0]=0.f;s[n][1]=0.f;s[n][2]=0.f;s[n][3]=0.f; }
    #pragma unroll
    for (int n=0;n<4;n++){
      f16x8 kf0 = *(const f16x8*)&Klds[16*n+llo][lhi*8];
      s[n] = __builtin_amdgcn_mfma_f32_16x16x32_f16(qf0, kf0, s[n], 0,0,0);
      f16x8 kf1 = *(const f16x8*)&Klds[16*n+llo][32+lhi*8];
      s[n] = __builtin_amdgcn_mfma_f32_16x16x32_f16(qf1, kf1, s[n], 0,0,0);
    }
    // online softmax: row r = lhi*4+j lives across the 16 lanes sharing lhi
    float pmax[4];
    #pragma unroll
    for (int j=0;j<4;j++)
      pmax[j] = fmaxf(fmaxf(s[0][j],s[1][j]), fmaxf(s[2][j],s[3][j]));
    #pragma unroll
    for (int off=1; off<16; off<<=1){
      #pragma unroll
      for (int j=0;j<4;j++) pmax[j] = fmaxf(pmax[j], __shfl_xor(pmax[j], off));
    }
    float esc[4];
    #pragma unroll
    for (int j=0;j<4;j++){
      float mnew = fmaxf(mrun[j], pmax[j]);
      esc[j] = __expf(mrun[j] - mnew);
      mrun[j] = mnew;
    }
    float p[4][4]; float lsum[4] = {0.f,0.f,0.f,0.f};
    #pragma unroll
    for (int n=0;n<4;n++)
      #pragma unroll
      for (int j=0;j<4;j++){
        p[n][j] = __expf(s[n][j] - mrun[j]);
        lsum[j] += p[n][j];
      }
    #pragma unroll
    for (int off=1; off<16; off<<=1){
      #pragma unroll
      for (int j=0;j<4;j++) lsum[j] += __shfl_xor(lsum[j], off);
    }
    #pragma unroll
    for (int j=0;j<4;j++) lrun[j] = lrun[j]*esc[j] + lsum[j];
    #pragma unroll
    for (int n=0;n<4;n++)
      #pragma unroll
      for (int j=0;j<4;j++) O[n][j] *= esc[j];

    // dropout: inline per-lane threefry (one eval per element, no cross-lane)
    // element index i = ((bh*2048 + q)*2048 + k), q = q0+wave*16+lhi*4+j, k = kv0+16n+llo
    const uint32_t ibase = (uint32_t)(((bh*2048 + q0 + wave*16 + lhi*4)*2048) + kv0) + (uint32_t)llo;
    #pragma unroll
    for (int j=0;j<4;j++){
      #pragma unroll
      for (int n=0;n<4;n++){
        uint32_t bits = tf_bits(ibase + (uint32_t)(j*2048 + n*16));
        float pm = tf_keep(bits) ? p[n][j]*(1.0f/0.9f) : 0.0f;
        Plds[wave][lhi*4+j][16*n+llo] = (f16)pm;
      }
    }
    f16x8 pa0 = *(const f16x8*)&Plds[wave][llo][lhi*8];
    f16x8 pa1 = *(const f16x8*)&Plds[wave][llo][32+lhi*8];
    #pragma unroll
    for (int n=0;n<4;n++){
      f16x8 vf0 = *(const f16x8*)&Vlds[16*n+llo][lhi*8];
      O[n] = __builtin_amdgcn_mfma_f32_16x16x32_f16(pa0, vf0, O[n], 0,0,0);
      f16x8 vf1 = *(const f16x8*)&Vlds[16*n+llo][32+lhi*8];
      O[n] = __builtin_amdgcn_mfma_f32_16x16x32_f16(pa1, vf1, O[n], 0,0,0);
    }
    __syncthreads();
  }

  // ---- fused epilogue: out[rows] = (O/l) @ Wo + bo, O staged f16 in Klds ----
  float rl[4];
  #pragma unroll
  for (int j=0;j<4;j++) rl[j] = 1.0f / lrun[j];
  #pragma unroll
  for (int n=0;n<4;n++)
    #pragma unroll
    for (int j=0;j<4;j++)
      Klds[wave*16 + lhi*4 + j][16*n + llo] = (f16)(O[n][j]*rl[j]);
  __syncthreads();

  f16x8 af0 = *(const f16x8*)&Klds[wave*16 + llo][lhi*8];
  f16x8 af1 = *(const f16x8*)&Klds[wave*16 + llo][32 + lhi*8];
  const long robase = (long)bh*2048 + q0 + wave*16 + lhi*4;
  for (int n0 = 0; n0 < 1024; n0 += 16){
    f16x8 b0 = *(const f16x8*)&WoT[(long)(n0+llo)*64 + lhi*8];
    f16x8 b1 = *(const f16x8*)&WoT[(long)(n0+llo)*64 + 32 + lhi*8];
    float bb = bo[n0+llo];
    f32x4 c; c[0]=bb; c[1]=bb; c[2]=bb; c[3]=bb;
    c = __builtin_amdgcn_mfma_f32_16x16x32_f16(af0, b0, c, 0,0,0);
    c = __builtin_amdgcn_mfma_f32_16x16x32_f16(af1, b1, c, 0,0,0);
    #pragma unroll
    for (int j=0;j<4;j++)
      out[(robase + j)*1024 + n0 + llo] = c[j];
  }
}

extern "C" void kernel_launch(void* const* d_in, const int* in_sizes, int n_in,
                              void* d_out, int out_size, void* d_ws, size_t ws_size,
                              hipStream_t stream){
  const float* query = (const float*)d_in[0];
  const float* key   = (const float*)d_in[1];
  const float* value = (const float*)d_in[2];
  const float* Wq = (const float*)d_in[3];
  const float* bq = (const float*)d_in[4];
  const float* Wk = (const float*)d_in[5];
  const float* bk = (const float*)d_in[6];
  const float* Wv = (const float*)d_in[7];
  const float* bv = (const float*)d_in[8];
  const float* Wo = (const float*)d_in[9];
  const float* bo = (const float*)d_in[10];
  float* out = (float*)d_out;

  char* ws = (char*)d_ws;
  f16* qp   = (f16*)(ws);                               // 4 MiB
  f16* kp   = (f16*)(ws + ((size_t)4<<20));             // 4 MiB
  f16* vpT  = (f16*)(ws + ((size_t)8<<20));             // 4 MiB
  f16* WoT  = (f16*)(ws + ((size_t)20<<20));            // 128 KiB

  proj_kernel<<<dim3(1792), dim3(256), 0, stream>>>(
      query,key,value,Wq,bq,Wk,bk,Wv,bv,Wo,qp,kp,vpT,WoT);
  flash_kernel<<<dim3(32,16), dim3(256), 0, stream>>>(qp,kp,vpT,WoT,bo,out);
}